// Round 1
// baseline (6091.241 us; speedup 1.0000x reference)
//
#include <hip/hip_runtime.h>
#include <cstdint>

#define NN  50000
#define MD  64
#define HD  128
#define RR  4
#define FD  7
#define EE  800000
#define BG  32
#define NMX 512

// ---------------------------------------------------------------------------
// Edge logits: out[b,n,k] = dot(z_dense[b,n,:], z_dense[b,k,:]) + bias
// 32x32 output tile per block, M=64 staged in LDS (pad 65 -> conflict-free).
// ---------------------------------------------------------------------------
__global__ __launch_bounds__(256) void edge_kernel(const float* __restrict__ zd,
                                                   const float* __restrict__ bias,
                                                   float* __restrict__ out) {
    __shared__ float As[32][65];
    __shared__ float Bs[32][65];
    const int b  = blockIdx.z;
    const int tn = blockIdx.y * 32;
    const int tk = blockIdx.x * 32;
    const float* zb = zd + (size_t)b * NMX * MD;
    const int tx = threadIdx.x, ty = threadIdx.y;
    const int t  = ty * 32 + tx;
    #pragma unroll
    for (int i = 0; i < 8; i++) {
        int flat = t + i * 256;
        int r = flat >> 6, c = flat & 63;
        As[r][c] = zb[(tn + r) * MD + c];
        Bs[r][c] = zb[(tk + r) * MD + c];
    }
    __syncthreads();
    float a0 = 0.f, a1 = 0.f, a2 = 0.f, a3 = 0.f;
    #pragma unroll
    for (int m = 0; m < MD; m++) {
        float bv = Bs[tx][m];
        a0 += As[ty     ][m] * bv;
        a1 += As[ty +  8][m] * bv;
        a2 += As[ty + 16][m] * bv;
        a3 += As[ty + 24][m] * bv;
    }
    const float bi = bias[0];
    size_t o = ((size_t)b * NMX + (tn + ty)) * NMX + tk + tx;
    out[o                     ] = a0 + bi;
    out[o + (size_t) 8 * NMX  ] = a1 + bi;
    out[o + (size_t)16 * NMX  ] = a2 + bi;
    out[o + (size_t)24 * NMX  ] = a3 + bi;
}

// ---------------------------------------------------------------------------
// Fused row-MLP: out[n,h] = (ADDIN? addin[n,h] : 0) + act(in[n,:] @ W + b)[h]
// W (K x 128) fully resident in LDS. 8 rows per block pass, each thread
// computes 4 rows x 1 h. Input rows stored transposed rs[K][8] so the 4-row
// fragment is one ds_read_b128.
// ---------------------------------------------------------------------------
template <int K, bool RELU, bool ADDIN>
__global__ __launch_bounds__(256) void mlp_kernel(const float* __restrict__ in,
                                                  const float* __restrict__ W,
                                                  const float* __restrict__ bvec,
                                                  float* __restrict__ out,
                                                  const float* __restrict__ addin,
                                                  int nrows) {
    __shared__ float Ws[K * HD];
    __shared__ float rs[K][8];
    const int tid = threadIdx.x;
    for (int i = tid; i < K * HD; i += 256) Ws[i] = W[i];
    const int h   = tid & (HD - 1);
    const int sub = tid >> 7;          // 0 or 1
    const int r0  = sub * 4;
    const float bval = bvec[h];

    for (int base = blockIdx.x * 8; base < nrows; base += gridDim.x * 8) {
        __syncthreads();
        for (int i = tid; i < 8 * K; i += 256) {
            int r = i / K, c = i % K;
            int n = base + r;
            rs[c][r] = (n < nrows) ? in[(size_t)n * K + c] : 0.f;
        }
        __syncthreads();
        float a0 = bval, a1 = bval, a2 = bval, a3 = bval;
        #pragma unroll 8
        for (int k = 0; k < K; k++) {
            float w = Ws[k * HD + h];
            float4 rv = *(const float4*)&rs[k][r0];
            a0 += rv.x * w;
            a1 += rv.y * w;
            a2 += rv.z * w;
            a3 += rv.w * w;
        }
        float accs[4] = {a0, a1, a2, a3};
        #pragma unroll
        for (int j = 0; j < 4; j++) {
            int n = base + r0 + j;
            if (n < nrows) {
                float v = accs[j];
                if constexpr (RELU)  v = fmaxf(v, 0.f);
                if constexpr (ADDIN) v += addin[(size_t)n * HD + h];
                out[(size_t)n * HD + h] = v;
            }
        }
    }
}

// ---------------------------------------------------------------------------
// Scatter-add: agg[dst[e], :] += msg[src[e], :].  32 threads/edge, float4.
// ---------------------------------------------------------------------------
__global__ __launch_bounds__(256) void scatter_kernel(const int* __restrict__ src,
                                                      const int* __restrict__ dst,
                                                      const float* __restrict__ msg,
                                                      float* __restrict__ agg) {
    size_t gt = (size_t)blockIdx.x * 256 + threadIdx.x;
    int e = (int)(gt >> 5);
    int j = (int)(gt & 31);
    if (e >= EE) return;
    int s = src[e], d = dst[e];
    float4 v = *(const float4*)(msg + (size_t)s * HD + j * 4);
    float* ap = agg + (size_t)d * HD + j * 4;
    atomicAdd(ap + 0, v.x);
    atomicAdd(ap + 1, v.y);
    atomicAdd(ap + 2, v.z);
    atomicAdd(ap + 3, v.w);
}

// ---------------------------------------------------------------------------
// Final projection: node_logits[n,f] = state[n,:] @ W_out[:,f] + b_out[f]
// ---------------------------------------------------------------------------
__global__ __launch_bounds__(256) void out_kernel(const float* __restrict__ state,
                                                  const float* __restrict__ W_out,
                                                  const float* __restrict__ b_out,
                                                  float* __restrict__ out) {
    __shared__ float Ws[HD * FD];
    __shared__ float bs[FD];
    const int tid = threadIdx.x;
    for (int i = tid; i < HD * FD; i += 256) Ws[i] = W_out[i];
    if (tid < FD) bs[tid] = b_out[tid];
    __syncthreads();
    int n = blockIdx.x * 256 + tid;
    if (n >= NN) return;
    float acc[FD];
    #pragma unroll
    for (int f = 0; f < FD; f++) acc[f] = bs[f];
    for (int k = 0; k < HD; k++) {
        float s = state[(size_t)n * HD + k];
        #pragma unroll
        for (int f = 0; f < FD; f++) acc[f] += s * Ws[k * FD + f];
    }
    #pragma unroll
    for (int f = 0; f < FD; f++) out[(size_t)n * FD + f] = acc[f];
}

extern "C" void kernel_launch(void* const* d_in, const int* in_sizes, int n_in,
                              void* d_out, int out_size, void* d_ws, size_t ws_size,
                              hipStream_t stream) {
    const float* z          = (const float*)d_in[0];
    const int*   edge_index = (const int*)  d_in[1];   // (2,E) row-major
    const float* z_dense    = (const float*)d_in[2];
    const float* bias       = (const float*)d_in[3];
    const float* W_in       = (const float*)d_in[4];
    const float* b_in       = (const float*)d_in[5];
    const float* W_msg      = (const float*)d_in[6];   // (R,H,H)
    const float* b_msg      = (const float*)d_in[7];   // (R,H)
    const float* W_upd      = (const float*)d_in[8];
    const float* b_upd      = (const float*)d_in[9];
    const float* W_out      = (const float*)d_in[10];  // (H,F)
    const float* b_out      = (const float*)d_in[11];

    float* out      = (float*)d_out;
    float* edge_out = out;                                   // 32*512*512
    float* node_out = out + (size_t)BG * NMX * NMX;          // 50000*7

    float* state   = (float*)d_ws;                           // N*H
    float* message = state   + (size_t)NN * HD;              // N*H
    float* agg     = message + (size_t)NN * HD;              // N*H

    const int* src = edge_index;
    const int* dst = edge_index + EE;

    // ---- edge logits ----
    dim3 eg(NMX / 32, NMX / 32, BG);
    dim3 eb(32, 8);
    edge_kernel<<<eg, eb, 0, stream>>>(z_dense, bias, edge_out);

    // ---- node pipeline ----
    const int MLP_GRID = 6250;                               // 6250*8 = 50000 rows
    mlp_kernel<MD, true, false><<<MLP_GRID, 256, 0, stream>>>(
        z, W_in, b_in, state, nullptr, NN);

    const int SC_GRID = (EE * 32 + 255) / 256;
    for (int r = 0; r < RR; r++) {
        mlp_kernel<HD, true, false><<<MLP_GRID, 256, 0, stream>>>(
            state, W_msg + (size_t)r * HD * HD, b_msg + (size_t)r * HD,
            message, nullptr, NN);
        hipMemsetAsync(agg, 0, (size_t)NN * HD * sizeof(float), stream);
        scatter_kernel<<<SC_GRID, 256, 0, stream>>>(src, dst, message, agg);
        mlp_kernel<HD, true, true><<<MLP_GRID, 256, 0, stream>>>(
            agg, W_upd + (size_t)r * HD * HD, b_upd + (size_t)r * HD,
            state, state, NN);
    }
    out_kernel<<<(NN + 255) / 256, 256, 0, stream>>>(state, W_out, b_out, node_out);
}

// Round 2
// 1152.266 us; speedup vs baseline: 5.2863x; 5.2863x over previous
//
#include <hip/hip_runtime.h>
#include <cstdint>

#define NN  50000
#define MD  64
#define HD  128
#define RR  4
#define FD  7
#define EE  800000
#define BG  32
#define NMX 512

// ---------------------------------------------------------------------------
// Edge logits: out[b,n,k] = dot(z_dense[b,n,:], z_dense[b,k,:]) + bias
// ---------------------------------------------------------------------------
__global__ __launch_bounds__(256) void edge_kernel(const float* __restrict__ zd,
                                                   const float* __restrict__ bias,
                                                   float* __restrict__ out) {
    __shared__ float As[32][65];
    __shared__ float Bs[32][65];
    const int b  = blockIdx.z;
    const int tn = blockIdx.y * 32;
    const int tk = blockIdx.x * 32;
    const float* zb = zd + (size_t)b * NMX * MD;
    const int tx = threadIdx.x, ty = threadIdx.y;
    const int t  = ty * 32 + tx;
    #pragma unroll
    for (int i = 0; i < 8; i++) {
        int flat = t + i * 256;
        int r = flat >> 6, c = flat & 63;
        As[r][c] = zb[(tn + r) * MD + c];
        Bs[r][c] = zb[(tk + r) * MD + c];
    }
    __syncthreads();
    float a0 = 0.f, a1 = 0.f, a2 = 0.f, a3 = 0.f;
    #pragma unroll
    for (int m = 0; m < MD; m++) {
        float bv = Bs[tx][m];
        a0 += As[ty     ][m] * bv;
        a1 += As[ty +  8][m] * bv;
        a2 += As[ty + 16][m] * bv;
        a3 += As[ty + 24][m] * bv;
    }
    const float bi = bias[0];
    size_t o = ((size_t)b * NMX + (tn + ty)) * NMX + tk + tx;
    out[o                     ] = a0 + bi;
    out[o + (size_t) 8 * NMX  ] = a1 + bi;
    out[o + (size_t)16 * NMX  ] = a2 + bi;
    out[o + (size_t)24 * NMX  ] = a3 + bi;
}

// ---------------------------------------------------------------------------
// Fused row-MLP (unchanged from R1 — VALU-bound, fine for now)
// ---------------------------------------------------------------------------
template <int K, bool RELU, bool ADDIN>
__global__ __launch_bounds__(256) void mlp_kernel(const float* __restrict__ in,
                                                  const float* __restrict__ W,
                                                  const float* __restrict__ bvec,
                                                  float* __restrict__ out,
                                                  const float* __restrict__ addin,
                                                  int nrows) {
    __shared__ float Ws[K * HD];
    __shared__ float rs[K][8];
    const int tid = threadIdx.x;
    for (int i = tid; i < K * HD; i += 256) Ws[i] = W[i];
    const int h   = tid & (HD - 1);
    const int sub = tid >> 7;
    const int r0  = sub * 4;
    const float bval = bvec[h];

    for (int base = blockIdx.x * 8; base < nrows; base += gridDim.x * 8) {
        __syncthreads();
        for (int i = tid; i < 8 * K; i += 256) {
            int r = i / K, c = i % K;
            int n = base + r;
            rs[c][r] = (n < nrows) ? in[(size_t)n * K + c] : 0.f;
        }
        __syncthreads();
        float a0 = bval, a1 = bval, a2 = bval, a3 = bval;
        #pragma unroll 8
        for (int k = 0; k < K; k++) {
            float w = Ws[k * HD + h];
            float4 rv = *(const float4*)&rs[k][r0];
            a0 += rv.x * w;
            a1 += rv.y * w;
            a2 += rv.z * w;
            a3 += rv.w * w;
        }
        float accs[4] = {a0, a1, a2, a3};
        #pragma unroll
        for (int j = 0; j < 4; j++) {
            int n = base + r0 + j;
            if (n < nrows) {
                float v = accs[j];
                if constexpr (RELU)  v = fmaxf(v, 0.f);
                if constexpr (ADDIN) v += addin[(size_t)n * HD + h];
                out[(size_t)n * HD + h] = v;
            }
        }
    }
}

// ---------------------------------------------------------------------------
// CSR build: histogram -> block scan -> global scan -> bucket scatter
// ---------------------------------------------------------------------------
__global__ __launch_bounds__(256) void hist_kernel(const int* __restrict__ dst,
                                                   int* __restrict__ cnt) {
    int e = blockIdx.x * 256 + threadIdx.x;
    if (e < EE) atomicAdd(&cnt[dst[e]], 1);
}

// per-256-chunk inclusive scan; writes incl[] and per-block totals
__global__ __launch_bounds__(256) void scan1_kernel(const int* __restrict__ cnt,
                                                    int* __restrict__ incl,
                                                    int* __restrict__ bsum) {
    __shared__ int s[256];
    int i = blockIdx.x * 256 + threadIdx.x;
    int t = threadIdx.x;
    s[t] = (i < NN) ? cnt[i] : 0;
    __syncthreads();
    #pragma unroll
    for (int off = 1; off < 256; off <<= 1) {
        int x = (t >= off) ? s[t - off] : 0;
        __syncthreads();
        s[t] += x;
        __syncthreads();
    }
    if (i < NN) incl[i] = s[t];
    if (t == 255) bsum[blockIdx.x] = s[255];
}

// single-block exclusive scan of block totals (nb <= 256)
__global__ __launch_bounds__(256) void scan2_kernel(int* __restrict__ bsum, int nb) {
    __shared__ int s[256];
    int t = threadIdx.x;
    int orig = (t < nb) ? bsum[t] : 0;
    s[t] = orig;
    __syncthreads();
    #pragma unroll
    for (int off = 1; off < 256; off <<= 1) {
        int x = (t >= off) ? s[t - off] : 0;
        __syncthreads();
        s[t] += x;
        __syncthreads();
    }
    if (t < nb) bsum[t] = s[t] - orig;   // exclusive
}

// row_ptr[i] = incl[i] - cnt[i] + bsum[blk]; cursor = row_ptr
__global__ __launch_bounds__(256) void scan3_kernel(const int* __restrict__ cnt,
                                                    const int* __restrict__ incl,
                                                    const int* __restrict__ bsum,
                                                    int* __restrict__ row_ptr,
                                                    int* __restrict__ cursor) {
    int i = blockIdx.x * 256 + threadIdx.x;
    if (i < NN) {
        int ex = incl[i] - cnt[i] + bsum[blockIdx.x];
        row_ptr[i] = ex;
        cursor[i]  = ex;
        if (i == 0) row_ptr[NN] = EE;
    }
}

__global__ __launch_bounds__(256) void bucket_kernel(const int* __restrict__ src,
                                                     const int* __restrict__ dst,
                                                     int* __restrict__ cursor,
                                                     int* __restrict__ colsrc) {
    int e = blockIdx.x * 256 + threadIdx.x;
    if (e < EE) {
        int pos = atomicAdd(&cursor[dst[e]], 1);
        colsrc[pos] = src[e];
    }
}

// ---------------------------------------------------------------------------
// Gather: agg[v,h] = sum_{j in [rp[v],rp[v+1])} msg[colsrc[j], h]
// 2 nodes per 256-block; 128 threads/node -> coalesced 512B row reads.
// ---------------------------------------------------------------------------
__global__ __launch_bounds__(256) void gather_kernel(const int* __restrict__ rp,
                                                     const int* __restrict__ colsrc,
                                                     const float* __restrict__ msg,
                                                     float* __restrict__ agg) {
    int v = blockIdx.x * 2 + (threadIdx.x >> 7);
    int h = threadIdx.x & 127;
    if (v >= NN) return;
    int beg = rp[v], end = rp[v + 1];
    float acc = 0.f, acc2 = 0.f;
    int j = beg;
    for (; j + 1 < end; j += 2) {
        int c0 = colsrc[j], c1 = colsrc[j + 1];
        acc  += msg[(size_t)c0 * HD + h];
        acc2 += msg[(size_t)c1 * HD + h];
    }
    if (j < end) acc += msg[(size_t)colsrc[j] * HD + h];
    agg[(size_t)v * HD + h] = acc + acc2;
}

// ---------------------------------------------------------------------------
// Final projection: wave-per-node, coalesced state reads, shuffle reduce.
// ---------------------------------------------------------------------------
__global__ __launch_bounds__(256) void out_kernel(const float* __restrict__ state,
                                                  const float* __restrict__ W_out,
                                                  const float* __restrict__ b_out,
                                                  float* __restrict__ out) {
    __shared__ float Ws[HD * FD];
    __shared__ float bs[FD];
    const int tid = threadIdx.x;
    for (int i = tid; i < HD * FD; i += 256) Ws[i] = W_out[i];
    if (tid < FD) bs[tid] = b_out[tid];
    __syncthreads();
    int v = blockIdx.x * 4 + (tid >> 6);
    int lane = tid & 63;
    if (v >= NN) return;
    float s0 = state[(size_t)v * HD + lane];
    float s1 = state[(size_t)v * HD + 64 + lane];
    float acc[FD];
    #pragma unroll
    for (int f = 0; f < FD; f++)
        acc[f] = s0 * Ws[lane * FD + f] + s1 * Ws[(lane + 64) * FD + f];
    #pragma unroll
    for (int off = 32; off > 0; off >>= 1) {
        #pragma unroll
        for (int f = 0; f < FD; f++) acc[f] += __shfl_down(acc[f], off);
    }
    if (lane == 0) {
        #pragma unroll
        for (int f = 0; f < FD; f++) out[(size_t)v * FD + f] = acc[f] + bs[f];
    }
}

extern "C" void kernel_launch(void* const* d_in, const int* in_sizes, int n_in,
                              void* d_out, int out_size, void* d_ws, size_t ws_size,
                              hipStream_t stream) {
    const float* z          = (const float*)d_in[0];
    const int*   edge_index = (const int*)  d_in[1];
    const float* z_dense    = (const float*)d_in[2];
    const float* bias       = (const float*)d_in[3];
    const float* W_in       = (const float*)d_in[4];
    const float* b_in       = (const float*)d_in[5];
    const float* W_msg      = (const float*)d_in[6];
    const float* b_msg      = (const float*)d_in[7];
    const float* W_upd      = (const float*)d_in[8];
    const float* b_upd      = (const float*)d_in[9];
    const float* W_out      = (const float*)d_in[10];
    const float* b_out      = (const float*)d_in[11];

    float* out      = (float*)d_out;
    float* edge_out = out;
    float* node_out = out + (size_t)BG * NMX * NMX;

    float* state   = (float*)d_ws;                           // N*H
    float* message = state   + (size_t)NN * HD;              // N*H
    float* agg     = message + (size_t)NN * HD;              // N*H
    int*   iws     = (int*)(agg + (size_t)NN * HD);
    int*   cnt     = iws;                                    // N (aliased cursor)
    int*   incl    = cnt  + NN;                              // N
    int*   row_ptr = incl + NN;                              // N+1
    int*   colsrc  = row_ptr + NN + 1;                       // E
    int*   bsum    = colsrc + EE;                            // 256

    const int* src = edge_index;
    const int* dst = edge_index + EE;

    const int NB = (NN + 255) / 256;   // 196
    const int EB = (EE + 255) / 256;

    // ---- edge logits ----
    dim3 eg(NMX / 32, NMX / 32, BG);
    dim3 eb(32, 8);
    edge_kernel<<<eg, eb, 0, stream>>>(z_dense, bias, edge_out);

    // ---- CSR build (once per launch) ----
    hipMemsetAsync(cnt, 0, NN * sizeof(int), stream);
    hist_kernel<<<EB, 256, 0, stream>>>(dst, cnt);
    scan1_kernel<<<NB, 256, 0, stream>>>(cnt, incl, bsum);
    scan2_kernel<<<1, 256, 0, stream>>>(bsum, NB);
    scan3_kernel<<<NB, 256, 0, stream>>>(cnt, incl, bsum, row_ptr, cnt /*cursor*/);
    bucket_kernel<<<EB, 256, 0, stream>>>(src, dst, cnt /*cursor*/, colsrc);

    // ---- node pipeline ----
    const int MLP_GRID = 6250;
    mlp_kernel<MD, true, false><<<MLP_GRID, 256, 0, stream>>>(
        z, W_in, b_in, state, nullptr, NN);

    const int GATHER_GRID = (NN + 1) / 2;
    for (int r = 0; r < RR; r++) {
        mlp_kernel<HD, true, false><<<MLP_GRID, 256, 0, stream>>>(
            state, W_msg + (size_t)r * HD * HD, b_msg + (size_t)r * HD,
            message, nullptr, NN);
        gather_kernel<<<GATHER_GRID, 256, 0, stream>>>(row_ptr, colsrc, message, agg);
        mlp_kernel<HD, true, true><<<MLP_GRID, 256, 0, stream>>>(
            agg, W_upd + (size_t)r * HD * HD, b_upd + (size_t)r * HD,
            state, state, NN);
    }
    out_kernel<<<(NN + 3) / 4, 256, 0, stream>>>(state, W_out, b_out, node_out);
}

// Round 3
// 546.875 us; speedup vs baseline: 11.1383x; 2.1070x over previous
//
#include <hip/hip_runtime.h>
#include <cstdint>

#define NN  50000
#define MD  64
#define HD  128
#define RR  4
#define FD  7
#define EE  800000
#define BG  32
#define NMX 512

typedef __attribute__((ext_vector_type(8))) short bf16x8;   // 8 bf16 (4 VGPRs)
typedef __attribute__((ext_vector_type(4))) float f32x4;

__device__ __forceinline__ unsigned short f2bf(float f) {
    unsigned u = __builtin_bit_cast(unsigned, f);
    u = (u + 0x7fffu + ((u >> 16) & 1u)) >> 16;
    return (unsigned short)u;
}
__device__ __forceinline__ float bflo(unsigned u) {
    return __builtin_bit_cast(float, u << 16);
}
__device__ __forceinline__ float bfhi(unsigned u) {
    return __builtin_bit_cast(float, u & 0xffff0000u);
}

// ---------------------------------------------------------------------------
// Edge logits: 64x64 tile per 256-block, K=64 fully LDS-resident.
// As/Bs stored [m][row] (pad 68) so inner reads are b128 broadcast/2-way.
// ---------------------------------------------------------------------------
__global__ __launch_bounds__(256) void edge_kernel(const float* __restrict__ zd,
                                                   const float* __restrict__ bias,
                                                   float* __restrict__ out) {
    __shared__ float As[MD][68];
    __shared__ float Bs[MD][68];
    const int b  = blockIdx.z;
    const int tn = blockIdx.y * 64;
    const int tk = blockIdx.x * 64;
    const float* zb = zd + (size_t)b * NMX * MD;
    const int t  = threadIdx.x;
    #pragma unroll
    for (int i = 0; i < 4; i++) {
        int r  = (t >> 4) + i * 16;
        int m0 = (t & 15) * 4;
        float4 va = *(const float4*)(zb + (size_t)(tn + r) * MD + m0);
        float4 vb = *(const float4*)(zb + (size_t)(tk + r) * MD + m0);
        As[m0][r] = va.x; As[m0+1][r] = va.y; As[m0+2][r] = va.z; As[m0+3][r] = va.w;
        Bs[m0][r] = vb.x; Bs[m0+1][r] = vb.y; Bs[m0+2][r] = vb.z; Bs[m0+3][r] = vb.w;
    }
    __syncthreads();
    const int tx = t & 15, ty = t >> 4;
    float acc[4][4];
    #pragma unroll
    for (int i = 0; i < 4; i++)
        #pragma unroll
        for (int j = 0; j < 4; j++) acc[i][j] = 0.f;
    for (int m = 0; m < MD; m++) {
        float4 av = *(const float4*)&As[m][ty * 4];
        float4 bv = *(const float4*)&Bs[m][tx * 4];
        float aa[4] = {av.x, av.y, av.z, av.w};
        float bb[4] = {bv.x, bv.y, bv.z, bv.w};
        #pragma unroll
        for (int i = 0; i < 4; i++)
            #pragma unroll
            for (int j = 0; j < 4; j++) acc[i][j] += aa[i] * bb[j];
    }
    const float bi = bias[0];
    #pragma unroll
    for (int i = 0; i < 4; i++) {
        float4 w = {acc[i][0] + bi, acc[i][1] + bi, acc[i][2] + bi, acc[i][3] + bi};
        size_t o = ((size_t)b * NMX + (tn + ty * 4 + i)) * NMX + tk + tx * 4;
        *(float4*)(out + o) = w;
    }
}

// ---------------------------------------------------------------------------
// Convert helpers (once per launch)
// ---------------------------------------------------------------------------
__global__ __launch_bounds__(256) void cvt_kernel(const float* __restrict__ src,
                                                  unsigned short* __restrict__ dst,
                                                  int n4) {   // n4 = n/4
    int i = blockIdx.x * 256 + threadIdx.x;
    if (i >= n4) return;
    float4 v = *(const float4*)(src + (size_t)i * 4);
    ushort4 o = {f2bf(v.x), f2bf(v.y), f2bf(v.z), f2bf(v.w)};
    *(ushort4*)(dst + (size_t)i * 4) = o;
}

// dst[r][h][k] = bf16(src[r][k][h])   (transpose-convert weights)
__global__ __launch_bounds__(256) void tcvt_kernel(const float* __restrict__ src,
                                                   unsigned short* __restrict__ dst,
                                                   int K, int H) {
    int r = blockIdx.y;
    int i = blockIdx.x * 256 + threadIdx.x;
    if (i >= K * H) return;
    int k = i / H, h = i % H;
    float v = src[(size_t)r * K * H + i];
    dst[(size_t)r * K * H + (size_t)h * K + k] = f2bf(v);
}

// ---------------------------------------------------------------------------
// MFMA MLP: out = relu(in @ W + b) [+ addin], in bf16 [n][K], Wt bf16 [128][K]
// 4 waves/block, wave = 16 rows x 128 cols; 8 col-tiles x (K/32) chunks.
// MODE: 0 = bf16 out only; 1 = fp32 + bf16 out; 2 = +addin(fp32), fp32 + bf16
// ---------------------------------------------------------------------------
template <int K, int MODE>
__global__ __launch_bounds__(256) void mfma_mlp_kernel(
    const unsigned short* __restrict__ in, const unsigned short* __restrict__ Wt,
    const float* __restrict__ bvec, const float* __restrict__ addin,
    float* __restrict__ out_f32, unsigned short* __restrict__ out_bf16, int nrows)
{
    constexpr int KC = K / 32;
    __shared__ float cstage[64][132];
    const int tid  = threadIdx.x;
    const int wave = tid >> 6;
    const int lane = tid & 63;
    const int r0   = blockIdx.x * 64 + wave * 16;
    const int l15  = lane & 15;
    const int k8   = (lane >> 4) * 8;

    int rclamp = min(r0 + l15, nrows - 1);
    const unsigned short* ap = in + (size_t)rclamp * K + k8;
    bf16x8 afrag[KC];
    #pragma unroll
    for (int c = 0; c < KC; c++) afrag[c] = *(const bf16x8*)(ap + c * 32);

    f32x4 acc[8];
    #pragma unroll
    for (int ct = 0; ct < 8; ct++) acc[ct] = (f32x4){0.f, 0.f, 0.f, 0.f};
    const unsigned short* bp = Wt + (size_t)l15 * K + k8;
    #pragma unroll
    for (int ct = 0; ct < 8; ct++) {
        #pragma unroll
        for (int c = 0; c < KC; c++) {
            bf16x8 bfrag = *(const bf16x8*)(bp + (size_t)ct * 16 * K + c * 32);
            acc[ct] = __builtin_amdgcn_mfma_f32_16x16x32_bf16(afrag[c], bfrag, acc[ct], 0, 0, 0);
        }
    }
    // C/D layout: col = lane&15, row = (lane>>4)*4 + i   [m89-verified]
    #pragma unroll
    for (int ct = 0; ct < 8; ct++)
        #pragma unroll
        for (int i = 0; i < 4; i++)
            cstage[wave * 16 + (lane >> 4) * 4 + i][ct * 16 + l15] = acc[ct][i];
    __syncthreads();

    const int rbase = blockIdx.x * 64;
    #pragma unroll
    for (int it = 0; it < 8; it++) {
        int f   = tid + it * 256;        // float4 index over 64x128
        int row = f >> 5, c4 = (f & 31) * 4;
        int grow = rbase + row;
        if (grow >= nrows) continue;
        float4 v  = *(const float4*)&cstage[row][c4];
        float4 bb = *(const float4*)(bvec + c4);
        v.x = fmaxf(v.x + bb.x, 0.f);
        v.y = fmaxf(v.y + bb.y, 0.f);
        v.z = fmaxf(v.z + bb.z, 0.f);
        v.w = fmaxf(v.w + bb.w, 0.f);
        if constexpr (MODE == 2) {
            float4 ad = *(const float4*)(addin + (size_t)grow * HD + c4);
            v.x += ad.x; v.y += ad.y; v.z += ad.z; v.w += ad.w;
        }
        if constexpr (MODE >= 1)
            *(float4*)(out_f32 + (size_t)grow * HD + c4) = v;
        ushort4 o = {f2bf(v.x), f2bf(v.y), f2bf(v.z), f2bf(v.w)};
        *(ushort4*)(out_bf16 + (size_t)grow * HD + c4) = o;
    }
}

// ---------------------------------------------------------------------------
// CSR build
// ---------------------------------------------------------------------------
__global__ __launch_bounds__(256) void hist_kernel(const int* __restrict__ dst,
                                                   int* __restrict__ cnt) {
    int e = blockIdx.x * 256 + threadIdx.x;
    if (e < EE) atomicAdd(&cnt[dst[e]], 1);
}

__global__ __launch_bounds__(256) void scan1_kernel(const int* __restrict__ cnt,
                                                    int* __restrict__ incl,
                                                    int* __restrict__ bsum) {
    __shared__ int s[256];
    int i = blockIdx.x * 256 + threadIdx.x;
    int t = threadIdx.x;
    s[t] = (i < NN) ? cnt[i] : 0;
    __syncthreads();
    #pragma unroll
    for (int off = 1; off < 256; off <<= 1) {
        int x = (t >= off) ? s[t - off] : 0;
        __syncthreads();
        s[t] += x;
        __syncthreads();
    }
    if (i < NN) incl[i] = s[t];
    if (t == 255) bsum[blockIdx.x] = s[255];
}

__global__ __launch_bounds__(256) void scan2_kernel(int* __restrict__ bsum, int nb) {
    __shared__ int s[256];
    int t = threadIdx.x;
    int orig = (t < nb) ? bsum[t] : 0;
    s[t] = orig;
    __syncthreads();
    #pragma unroll
    for (int off = 1; off < 256; off <<= 1) {
        int x = (t >= off) ? s[t - off] : 0;
        __syncthreads();
        s[t] += x;
        __syncthreads();
    }
    if (t < nb) bsum[t] = s[t] - orig;
}

__global__ __launch_bounds__(256) void scan3_kernel(const int* __restrict__ cnt,
                                                    const int* __restrict__ incl,
                                                    const int* __restrict__ bsum,
                                                    int* __restrict__ row_ptr,
                                                    int* __restrict__ cursor) {
    int i = blockIdx.x * 256 + threadIdx.x;
    if (i < NN) {
        int ex = incl[i] - cnt[i] + bsum[blockIdx.x];
        row_ptr[i] = ex;
        cursor[i]  = ex;
        if (i == 0) row_ptr[NN] = EE;
    }
}

__global__ __launch_bounds__(256) void bucket_kernel(const int* __restrict__ src,
                                                     const int* __restrict__ dst,
                                                     int* __restrict__ cursor,
                                                     int* __restrict__ colsrc) {
    int e = blockIdx.x * 256 + threadIdx.x;
    if (e < EE) {
        int pos = atomicAdd(&cursor[dst[e]], 1);
        colsrc[pos] = src[e];
    }
}

// ---------------------------------------------------------------------------
// Gather (bf16): wave per node; lane owns h={2*lane, 2*lane+1}; one u32/edge.
// ---------------------------------------------------------------------------
__global__ __launch_bounds__(256) void gather_kernel(const int* __restrict__ rp,
                                                     const int* __restrict__ colsrc,
                                                     const unsigned short* __restrict__ msg,
                                                     unsigned short* __restrict__ agg) {
    int v = blockIdx.x * 4 + (threadIdx.x >> 6);
    int lane = threadIdx.x & 63;
    if (v >= NN) return;
    int beg = rp[v], end = rp[v + 1];
    float a0 = 0.f, a1 = 0.f, b0 = 0.f, b1 = 0.f;
    int j = beg;
    for (; j + 1 < end; j += 2) {
        unsigned u0 = *(const unsigned*)(msg + (size_t)colsrc[j]     * HD + lane * 2);
        unsigned u1 = *(const unsigned*)(msg + (size_t)colsrc[j + 1] * HD + lane * 2);
        a0 += bflo(u0); a1 += bfhi(u0);
        b0 += bflo(u1); b1 += bfhi(u1);
    }
    if (j < end) {
        unsigned u = *(const unsigned*)(msg + (size_t)colsrc[j] * HD + lane * 2);
        a0 += bflo(u); a1 += bfhi(u);
    }
    unsigned o = (unsigned)f2bf(a0 + b0) | ((unsigned)f2bf(a1 + b1) << 16);
    *(unsigned*)(agg + (size_t)v * HD + lane * 2) = o;
}

// ---------------------------------------------------------------------------
// Final projection (fp32 state): wave per node, shuffle reduce.
// ---------------------------------------------------------------------------
__global__ __launch_bounds__(256) void out_kernel(const float* __restrict__ state,
                                                  const float* __restrict__ W_out,
                                                  const float* __restrict__ b_out,
                                                  float* __restrict__ out) {
    __shared__ float Ws[HD * FD];
    __shared__ float bs[FD];
    const int tid = threadIdx.x;
    for (int i = tid; i < HD * FD; i += 256) Ws[i] = W_out[i];
    if (tid < FD) bs[tid] = b_out[tid];
    __syncthreads();
    int v = blockIdx.x * 4 + (tid >> 6);
    int lane = tid & 63;
    if (v >= NN) return;
    float s0 = state[(size_t)v * HD + lane];
    float s1 = state[(size_t)v * HD + 64 + lane];
    float acc[FD];
    #pragma unroll
    for (int f = 0; f < FD; f++)
        acc[f] = s0 * Ws[lane * FD + f] + s1 * Ws[(lane + 64) * FD + f];
    #pragma unroll
    for (int off = 32; off > 0; off >>= 1) {
        #pragma unroll
        for (int f = 0; f < FD; f++) acc[f] += __shfl_down(acc[f], off);
    }
    if (lane == 0) {
        #pragma unroll
        for (int f = 0; f < FD; f++) out[(size_t)v * FD + f] = acc[f] + bs[f];
    }
}

extern "C" void kernel_launch(void* const* d_in, const int* in_sizes, int n_in,
                              void* d_out, int out_size, void* d_ws, size_t ws_size,
                              hipStream_t stream) {
    const float* z          = (const float*)d_in[0];
    const int*   edge_index = (const int*)  d_in[1];
    const float* z_dense    = (const float*)d_in[2];
    const float* bias       = (const float*)d_in[3];
    const float* W_in       = (const float*)d_in[4];
    const float* b_in       = (const float*)d_in[5];
    const float* W_msg      = (const float*)d_in[6];
    const float* b_msg      = (const float*)d_in[7];
    const float* W_upd      = (const float*)d_in[8];
    const float* b_upd      = (const float*)d_in[9];
    const float* W_out      = (const float*)d_in[10];
    const float* b_out      = (const float*)d_in[11];

    float* out      = (float*)d_out;
    float* edge_out = out;
    float* node_out = out + (size_t)BG * NMX * NMX;

    // ---- workspace layout ----
    char* p = (char*)d_ws;
    float* state = (float*)p;              p += (size_t)NN * HD * 4;   // fp32 master
    unsigned short* stateb = (unsigned short*)p; p += (size_t)NN * HD * 2;
    unsigned short* msgb   = (unsigned short*)p; p += (size_t)NN * HD * 2;
    unsigned short* aggb   = (unsigned short*)p; p += (size_t)NN * HD * 2;
    unsigned short* zb     = (unsigned short*)p; p += (size_t)NN * MD * 2;
    unsigned short* wt_in  = (unsigned short*)p; p += (size_t)HD * MD * 2;
    unsigned short* wt_msg = (unsigned short*)p; p += (size_t)RR * HD * HD * 2;
    unsigned short* wt_upd = (unsigned short*)p; p += (size_t)RR * HD * HD * 2;
    int* cnt     = (int*)p;                p += (size_t)NN * 4;
    int* incl    = (int*)p;                p += (size_t)NN * 4;
    int* row_ptr = (int*)p;                p += (size_t)(NN + 1) * 4;
    int* colsrc  = (int*)p;                p += (size_t)EE * 4;
    int* bsum    = (int*)p;

    const int* src = edge_index;
    const int* dst = edge_index + EE;
    const int NB = (NN + 255) / 256;
    const int EB = (EE + 255) / 256;

    // ---- edge logits ----
    dim3 eg(NMX / 64, NMX / 64, BG);
    edge_kernel<<<eg, 256, 0, stream>>>(z_dense, bias, edge_out);

    // ---- convert inputs/weights to bf16 (Wt transposed) ----
    cvt_kernel<<<(NN * MD / 4 + 255) / 256, 256, 0, stream>>>(z, zb, NN * MD / 4);
    tcvt_kernel<<<dim3((MD * HD + 255) / 256, 1), 256, 0, stream>>>(W_in, wt_in, MD, HD);
    tcvt_kernel<<<dim3((HD * HD + 255) / 256, RR), 256, 0, stream>>>(W_msg, wt_msg, HD, HD);
    tcvt_kernel<<<dim3((HD * HD + 255) / 256, RR), 256, 0, stream>>>(W_upd, wt_upd, HD, HD);

    // ---- CSR build ----
    hipMemsetAsync(cnt, 0, NN * sizeof(int), stream);
    hist_kernel<<<EB, 256, 0, stream>>>(dst, cnt);
    scan1_kernel<<<NB, 256, 0, stream>>>(cnt, incl, bsum);
    scan2_kernel<<<1, 256, 0, stream>>>(bsum, NB);
    scan3_kernel<<<NB, 256, 0, stream>>>(cnt, incl, bsum, row_ptr, cnt);
    bucket_kernel<<<EB, 256, 0, stream>>>(src, dst, cnt, colsrc);

    // ---- node pipeline ----
    const int MG = (NN + 63) / 64;   // 782
    mfma_mlp_kernel<MD, 1><<<MG, 256, 0, stream>>>(
        zb, wt_in, b_in, nullptr, state, stateb, NN);

    const int GG = (NN + 3) / 4;
    for (int r = 0; r < RR; r++) {
        mfma_mlp_kernel<HD, 0><<<MG, 256, 0, stream>>>(
            stateb, wt_msg + (size_t)r * HD * HD, b_msg + (size_t)r * HD,
            nullptr, nullptr, msgb, NN);
        gather_kernel<<<GG, 256, 0, stream>>>(row_ptr, colsrc, msgb, aggb);
        mfma_mlp_kernel<HD, 2><<<MG, 256, 0, stream>>>(
            aggb, wt_upd + (size_t)r * HD * HD, b_upd + (size_t)r * HD,
            state, state, stateb, NN);
    }
    out_kernel<<<(NN + 3) / 4, 256, 0, stream>>>(state, W_out, b_out, node_out);
}

// Round 5
// 516.117 us; speedup vs baseline: 11.8020x; 1.0596x over previous
//
#include <hip/hip_runtime.h>
#include <cstdint>

#define NN  50000
#define MD  64
#define HD  128
#define RR  4
#define FD  7
#define EE  800000
#define BG  32
#define NMX 512
#define GNB ((NN + 15) / 16)   // 3125 blocks per gather pass
#define NPASS 4                 // h-slices of 32 cols (64 B) -> 3.2 MB working set / pass

typedef __attribute__((ext_vector_type(8))) short bf16x8;
typedef __attribute__((ext_vector_type(4))) float f32x4;

__device__ __forceinline__ unsigned short f2bf(float f) {
    unsigned u = __builtin_bit_cast(unsigned, f);
    u = (u + 0x7fffu + ((u >> 16) & 1u)) >> 16;
    return (unsigned short)u;
}
__device__ __forceinline__ float bflo(unsigned u) { return __builtin_bit_cast(float, u << 16); }
__device__ __forceinline__ float bfhi(unsigned u) { return __builtin_bit_cast(float, u & 0xffff0000u); }

__device__ __forceinline__ bf16x8 pack8(float4 a, float4 b) {
    bf16x8 r;
    r[0]=(short)f2bf(a.x); r[1]=(short)f2bf(a.y); r[2]=(short)f2bf(a.z); r[3]=(short)f2bf(a.w);
    r[4]=(short)f2bf(b.x); r[5]=(short)f2bf(b.y); r[6]=(short)f2bf(b.z); r[7]=(short)f2bf(b.w);
    return r;
}

// ---------------------------------------------------------------------------
// Edge logits via bf16 MFMA: C = Z Z^T + bias. 64x64 tile / 256-block.
// ---------------------------------------------------------------------------
__global__ __launch_bounds__(256) void edge_kernel(const unsigned short* __restrict__ zdb,
                                                   const float* __restrict__ bias,
                                                   float* __restrict__ out) {
    __shared__ float cstage[64][68];
    const int b  = blockIdx.z;
    const int tn = blockIdx.y * 64;
    const int tk = blockIdx.x * 64;
    const unsigned short* zb = zdb + (size_t)b * NMX * MD;
    const int tid = threadIdx.x, wave = tid >> 6, lane = tid & 63;
    const int l15 = lane & 15, k8 = (lane >> 4) * 8;

    const unsigned short* ap = zb + (size_t)(tn + wave * 16 + l15) * MD + k8;
    bf16x8 af0 = *(const bf16x8*)ap;
    bf16x8 af1 = *(const bf16x8*)(ap + 32);

    f32x4 acc[4];
    #pragma unroll
    for (int ct = 0; ct < 4; ct++) acc[ct] = (f32x4){0.f, 0.f, 0.f, 0.f};
    const unsigned short* bp = zb + (size_t)(tk + l15) * MD + k8;
    #pragma unroll
    for (int ct = 0; ct < 4; ct++) {
        bf16x8 b0 = *(const bf16x8*)(bp + (size_t)ct * 16 * MD);
        bf16x8 b1 = *(const bf16x8*)(bp + (size_t)ct * 16 * MD + 32);
        acc[ct] = __builtin_amdgcn_mfma_f32_16x16x32_bf16(af0, b0, acc[ct], 0, 0, 0);
        acc[ct] = __builtin_amdgcn_mfma_f32_16x16x32_bf16(af1, b1, acc[ct], 0, 0, 0);
    }
    #pragma unroll
    for (int ct = 0; ct < 4; ct++)
        #pragma unroll
        for (int i = 0; i < 4; i++)
            cstage[wave * 16 + (lane >> 4) * 4 + i][ct * 16 + l15] = acc[ct][i];
    __syncthreads();
    const float bi = bias[0];
    #pragma unroll
    for (int it = 0; it < 4; it++) {
        int f = tid + it * 256;
        int row = f >> 4, c4 = (f & 15) * 4;
        float4 v = *(const float4*)&cstage[row][c4];
        v.x += bi; v.y += bi; v.z += bi; v.w += bi;
        *(float4*)(out + ((size_t)b * NMX + tn + row) * NMX + tk + c4) = v;
    }
}

// ---------------------------------------------------------------------------
// Converters
// ---------------------------------------------------------------------------
__global__ __launch_bounds__(256) void cvt_kernel(const float* __restrict__ src,
                                                  unsigned short* __restrict__ dst,
                                                  int n4) {
    int i = blockIdx.x * 256 + threadIdx.x;
    if (i >= n4) return;
    float4 v = *(const float4*)(src + (size_t)i * 4);
    ushort4 o = {f2bf(v.x), f2bf(v.y), f2bf(v.z), f2bf(v.w)};
    *(ushort4*)(dst + (size_t)i * 4) = o;
}

__global__ __launch_bounds__(256) void tcvt_kernel(const float* __restrict__ src,
                                                   unsigned short* __restrict__ dst,
                                                   int K, int H) {
    int r = blockIdx.y;
    int i = blockIdx.x * 256 + threadIdx.x;
    if (i >= K * H) return;
    int k = i / H, h = i % H;
    float v = src[(size_t)r * K * H + i];
    dst[(size_t)r * K * H + (size_t)h * K + k] = f2bf(v);
}

// ---------------------------------------------------------------------------
// Fused MLP (two MFMA stages; see R3 notes). MODE 2 out-projection FIXED:
// 64*FD=448 work items now covered by a 256-thread strided loop.
// ---------------------------------------------------------------------------
template <int K1, int MODE, bool BLK>
__global__ __launch_bounds__(256) void fused_kernel(
    const unsigned short* __restrict__ in,
    const unsigned short* __restrict__ Wt1,
    const float* __restrict__ b1,
    float* __restrict__ state,
    const unsigned short* __restrict__ Wt2,
    const float* __restrict__ b2,
    unsigned short* __restrict__ msgb,
    const float* __restrict__ Wout,
    const float* __restrict__ bout,
    float* __restrict__ node_out,
    int nrows)
{
    constexpr int KC1 = K1 / 32;
    __shared__ float cstage[64][132];
    __shared__ float sWout[MODE == 2 ? HD * FD : 1];
    const int tid = threadIdx.x, wave = tid >> 6, lane = tid & 63;
    const int l15 = lane & 15, k8 = (lane >> 4) * 8;
    const int rbase = blockIdx.x * 64;

    if constexpr (MODE == 2)
        for (int i = tid; i < HD * FD; i += 256) sWout[i] = Wout[i];

    // ---- stage 1 MFMA ----
    int rclamp = min(rbase + wave * 16 + l15, nrows - 1);
    bf16x8 af[KC1];
    #pragma unroll
    for (int c = 0; c < KC1; c++) {
        size_t off = BLK ? ((size_t)c * NN * 32 + (size_t)rclamp * 32 + k8)
                         : ((size_t)rclamp * K1 + (size_t)c * 32 + k8);
        af[c] = *(const bf16x8*)(in + off);
    }
    f32x4 acc[8];
    #pragma unroll
    for (int ct = 0; ct < 8; ct++) acc[ct] = (f32x4){0.f, 0.f, 0.f, 0.f};
    const unsigned short* bp = Wt1 + (size_t)l15 * K1 + k8;
    #pragma unroll
    for (int ct = 0; ct < 8; ct++)
        #pragma unroll
        for (int c = 0; c < KC1; c++) {
            bf16x8 bf = *(const bf16x8*)(bp + (size_t)ct * 16 * K1 + c * 32);
            acc[ct] = __builtin_amdgcn_mfma_f32_16x16x32_bf16(af[c], bf, acc[ct], 0, 0, 0);
        }
    #pragma unroll
    for (int ct = 0; ct < 8; ct++)
        #pragma unroll
        for (int i = 0; i < 4; i++)
            cstage[wave * 16 + (lane >> 4) * 4 + i][ct * 16 + l15] = acc[ct][i];
    __syncthreads();

    // ---- epilogue 1: bias+relu (+state_old) -> state_new ----
    #pragma unroll
    for (int it = 0; it < 8; it++) {
        int f = tid + it * 256;
        int row = f >> 5, c4 = (f & 31) * 4;
        int grow = rbase + row;
        if (grow < nrows) {
            float4 v = *(const float4*)&cstage[row][c4];
            float4 bb = *(const float4*)(b1 + c4);
            v.x = fmaxf(v.x + bb.x, 0.f);
            v.y = fmaxf(v.y + bb.y, 0.f);
            v.z = fmaxf(v.z + bb.z, 0.f);
            v.w = fmaxf(v.w + bb.w, 0.f);
            if constexpr (MODE >= 1) {
                float4 so = *(const float4*)(state + (size_t)grow * HD + c4);
                v.x += so.x; v.y += so.y; v.z += so.z; v.w += so.w;
            }
            if constexpr (MODE <= 1)
                *(float4*)(state + (size_t)grow * HD + c4) = v;
            *(float4*)&cstage[row][c4] = v;
        }
    }
    __syncthreads();

    if constexpr (MODE <= 1) {
        // ---- stage 2 MFMA: A-frags from updated cstage ----
        bf16x8 af2[4];
        #pragma unroll
        for (int c = 0; c < 4; c++) {
            float4 u0 = *(const float4*)&cstage[wave * 16 + l15][c * 32 + k8];
            float4 u1 = *(const float4*)&cstage[wave * 16 + l15][c * 32 + k8 + 4];
            af2[c] = pack8(u0, u1);
        }
        f32x4 acc2[8];
        #pragma unroll
        for (int ct = 0; ct < 8; ct++) acc2[ct] = (f32x4){0.f, 0.f, 0.f, 0.f};
        const unsigned short* bp2 = Wt2 + (size_t)l15 * HD + k8;
        #pragma unroll
        for (int ct = 0; ct < 8; ct++)
            #pragma unroll
            for (int c = 0; c < 4; c++) {
                bf16x8 bf = *(const bf16x8*)(bp2 + (size_t)ct * 16 * HD + c * 32);
                acc2[ct] = __builtin_amdgcn_mfma_f32_16x16x32_bf16(af2[c], bf, acc2[ct], 0, 0, 0);
            }
        __syncthreads();
        #pragma unroll
        for (int ct = 0; ct < 8; ct++)
            #pragma unroll
            for (int i = 0; i < 4; i++)
                cstage[wave * 16 + (lane >> 4) * 4 + i][ct * 16 + l15] = acc2[ct][i];
        __syncthreads();
        #pragma unroll
        for (int it = 0; it < 8; it++) {
            int f = tid + it * 256;
            int row = f >> 5, c4 = (f & 31) * 4;
            int grow = rbase + row;
            if (grow < nrows) {
                float4 v = *(const float4*)&cstage[row][c4];
                float4 bb = *(const float4*)(b2 + c4);
                v.x = fmaxf(v.x + bb.x, 0.f);
                v.y = fmaxf(v.y + bb.y, 0.f);
                v.z = fmaxf(v.z + bb.z, 0.f);
                v.w = fmaxf(v.w + bb.w, 0.f);
                ushort4 o = {f2bf(v.x), f2bf(v.y), f2bf(v.z), f2bf(v.w)};
                size_t off = (size_t)(c4 >> 5) * NN * 32 + (size_t)grow * 32 + (c4 & 31);
                *(ushort4*)(msgb + off) = o;
            }
        }
    } else {
        // ---- out projection: 64 rows x 7 cols, 448 items, strided over 256 ----
        for (int i = tid; i < 64 * FD; i += 256) {
            int row = i / FD, ff = i - row * FD;
            int grow = rbase + row;
            if (grow < nrows) {
                float a = bout[ff];
                #pragma unroll 8
                for (int k = 0; k < HD; k++)
                    a += cstage[row][k] * sWout[k * FD + ff];
                node_out[(size_t)grow * FD + ff] = a;
            }
        }
    }
}

// ---------------------------------------------------------------------------
// CSR build
// ---------------------------------------------------------------------------
__global__ __launch_bounds__(256) void hist_kernel(const int* __restrict__ dst,
                                                   int* __restrict__ cnt) {
    int e = blockIdx.x * 256 + threadIdx.x;
    if (e < EE) atomicAdd(&cnt[dst[e]], 1);
}

__global__ __launch_bounds__(256) void scan1_kernel(const int* __restrict__ cnt,
                                                    int* __restrict__ incl,
                                                    int* __restrict__ bsum) {
    __shared__ int s[256];
    int i = blockIdx.x * 256 + threadIdx.x;
    int t = threadIdx.x;
    s[t] = (i < NN) ? cnt[i] : 0;
    __syncthreads();
    #pragma unroll
    for (int off = 1; off < 256; off <<= 1) {
        int x = (t >= off) ? s[t - off] : 0;
        __syncthreads();
        s[t] += x;
        __syncthreads();
    }
    if (i < NN) incl[i] = s[t];
    if (t == 255) bsum[blockIdx.x] = s[255];
}

__global__ __launch_bounds__(256) void scan2_kernel(int* __restrict__ bsum, int nb) {
    __shared__ int s[256];
    int t = threadIdx.x;
    int orig = (t < nb) ? bsum[t] : 0;
    s[t] = orig;
    __syncthreads();
    #pragma unroll
    for (int off = 1; off < 256; off <<= 1) {
        int x = (t >= off) ? s[t - off] : 0;
        __syncthreads();
        s[t] += x;
        __syncthreads();
    }
    if (t < nb) bsum[t] = s[t] - orig;
}

__global__ __launch_bounds__(256) void scan3_kernel(const int* __restrict__ cnt,
                                                    const int* __restrict__ incl,
                                                    const int* __restrict__ bsum,
                                                    int* __restrict__ row_ptr,
                                                    int* __restrict__ cursor) {
    int i = blockIdx.x * 256 + threadIdx.x;
    if (i < NN) {
        int ex = incl[i] - cnt[i] + bsum[blockIdx.x];
        row_ptr[i] = ex;
        cursor[i]  = ex;
        if (i == 0) row_ptr[NN] = EE;
    }
}

__global__ __launch_bounds__(256) void bucket_kernel(const int* __restrict__ src,
                                                     const int* __restrict__ dst,
                                                     int* __restrict__ cursor,
                                                     int* __restrict__ colsrc) {
    int e = blockIdx.x * 256 + threadIdx.x;
    if (e < EE) {
        int pos = atomicAdd(&cursor[dst[e]], 1);
        colsrc[pos] = src[e];
    }
}

// ---------------------------------------------------------------------------
// Pass-split gather (L2-resident slices)
// ---------------------------------------------------------------------------
__global__ __launch_bounds__(256) void gather_kernel(const int* __restrict__ rp,
                                                     const int* __restrict__ colsrc,
                                                     const unsigned* __restrict__ msgU,
                                                     unsigned* __restrict__ aggU) {
    int pass = blockIdx.x / GNB;
    int nb   = blockIdx.x - pass * GNB;
    int v    = nb * 16 + (threadIdx.x >> 4);
    int l    = threadIdx.x & 15;
    if (v >= NN) return;
    int beg = rp[v], end = rp[v + 1];
    const unsigned* base = msgU + (size_t)pass * NN * 16 + l;
    float a0 = 0.f, a1 = 0.f, b0 = 0.f, b1 = 0.f;
    int j = beg;
    for (; j + 1 < end; j += 2) {
        unsigned u0 = base[(size_t)colsrc[j]     * 16];
        unsigned u1 = base[(size_t)colsrc[j + 1] * 16];
        a0 += bflo(u0); a1 += bfhi(u0);
        b0 += bflo(u1); b1 += bfhi(u1);
    }
    if (j < end) {
        unsigned u = base[(size_t)colsrc[j] * 16];
        a0 += bflo(u); a1 += bfhi(u);
    }
    aggU[(size_t)pass * NN * 16 + (size_t)v * 16 + l] =
        (unsigned)f2bf(a0 + b0) | ((unsigned)f2bf(a1 + b1) << 16);
}

extern "C" void kernel_launch(void* const* d_in, const int* in_sizes, int n_in,
                              void* d_out, int out_size, void* d_ws, size_t ws_size,
                              hipStream_t stream) {
    const float* z          = (const float*)d_in[0];
    const int*   edge_index = (const int*)  d_in[1];
    const float* z_dense    = (const float*)d_in[2];
    const float* bias       = (const float*)d_in[3];
    const float* W_in       = (const float*)d_in[4];
    const float* b_in       = (const float*)d_in[5];
    const float* W_msg      = (const float*)d_in[6];
    const float* b_msg      = (const float*)d_in[7];
    const float* W_upd      = (const float*)d_in[8];
    const float* b_upd      = (const float*)d_in[9];
    const float* W_out      = (const float*)d_in[10];
    const float* b_out      = (const float*)d_in[11];

    float* out      = (float*)d_out;
    float* edge_out = out;
    float* node_out = out + (size_t)BG * NMX * NMX;

    // ---- workspace ----
    char* p = (char*)d_ws;
    float* state = (float*)p;                     p += (size_t)NN * HD * 4;
    unsigned short* msgb   = (unsigned short*)p;  p += (size_t)NN * HD * 2;
    unsigned short* aggb   = (unsigned short*)p;  p += (size_t)NN * HD * 2;
    unsigned short* zb     = (unsigned short*)p;  p += (size_t)NN * MD * 2;
    unsigned short* zdb    = (unsigned short*)p;  p += (size_t)BG * NMX * MD * 2;
    unsigned short* wt_in  = (unsigned short*)p;  p += (size_t)HD * MD * 2;
    unsigned short* wt_msg = (unsigned short*)p;  p += (size_t)RR * HD * HD * 2;
    unsigned short* wt_upd = (unsigned short*)p;  p += (size_t)RR * HD * HD * 2;
    int* cnt     = (int*)p;                       p += (size_t)NN * 4;
    int* incl    = (int*)p;                       p += (size_t)NN * 4;
    int* row_ptr = (int*)p;                       p += (size_t)(NN + 1) * 4;
    int* colsrc  = (int*)p;                       p += (size_t)EE * 4;
    int* bsum    = (int*)p;

    const int* src = edge_index;
    const int* dst = edge_index + EE;
    const int NB = (NN + 255) / 256;
    const int EB = (EE + 255) / 256;

    // ---- edge path ----
    cvt_kernel<<<(BG * NMX * MD / 4 + 255) / 256, 256, 0, stream>>>(
        z_dense, zdb, BG * NMX * MD / 4);
    dim3 eg(NMX / 64, NMX / 64, BG);
    edge_kernel<<<eg, 256, 0, stream>>>(zdb, bias, edge_out);

    // ---- conversions ----
    cvt_kernel<<<(NN * MD / 4 + 255) / 256, 256, 0, stream>>>(z, zb, NN * MD / 4);
    tcvt_kernel<<<dim3((MD * HD + 255) / 256, 1), 256, 0, stream>>>(W_in, wt_in, MD, HD);
    tcvt_kernel<<<dim3((HD * HD + 255) / 256, RR), 256, 0, stream>>>(W_msg, wt_msg, HD, HD);
    tcvt_kernel<<<dim3((HD * HD + 255) / 256, RR), 256, 0, stream>>>(W_upd, wt_upd, HD, HD);

    // ---- CSR build ----
    hipMemsetAsync(cnt, 0, NN * sizeof(int), stream);
    hist_kernel<<<EB, 256, 0, stream>>>(dst, cnt);
    scan1_kernel<<<NB, 256, 0, stream>>>(cnt, incl, bsum);
    scan2_kernel<<<1, 256, 0, stream>>>(bsum, NB);
    scan3_kernel<<<NB, 256, 0, stream>>>(cnt, incl, bsum, row_ptr, cnt);
    bucket_kernel<<<EB, 256, 0, stream>>>(src, dst, cnt, colsrc);

    // ---- node pipeline ----
    const int MG = (NN + 63) / 64;
    const int GG = NPASS * GNB;

    fused_kernel<MD, 0, false><<<MG, 256, 0, stream>>>(
        zb, wt_in, b_in, state,
        wt_msg, b_msg, msgb, nullptr, nullptr, nullptr, NN);

    for (int r = 0; r < RR - 1; r++) {
        gather_kernel<<<GG, 256, 0, stream>>>(row_ptr, colsrc, (const unsigned*)msgb,
                                              (unsigned*)aggb);
        fused_kernel<HD, 1, true><<<MG, 256, 0, stream>>>(
            aggb, wt_upd + (size_t)r * HD * HD, b_upd + (size_t)r * HD, state,
            wt_msg + (size_t)(r + 1) * HD * HD, b_msg + (size_t)(r + 1) * HD,
            msgb, nullptr, nullptr, nullptr, NN);
    }
    gather_kernel<<<GG, 256, 0, stream>>>(row_ptr, colsrc, (const unsigned*)msgb,
                                          (unsigned*)aggb);
    fused_kernel<HD, 2, true><<<MG, 256, 0, stream>>>(
        aggb, wt_upd + (size_t)(RR - 1) * HD * HD, b_upd + (size_t)(RR - 1) * HD, state,
        nullptr, nullptr, nullptr, W_out, b_out, node_out, NN);
}